// Round 1
// baseline (720.513 us; speedup 1.0000x reference)
//
#include <hip/hip_runtime.h>
#include <stdint.h>

#define Bdim 8
#define Tdim 1024
#define Cdim 768
#define Hdim 12
#define HDdim 64
#define NROW (Bdim*Tdim)   // 8192

typedef __attribute__((ext_vector_type(8))) short s16x8;
typedef __attribute__((ext_vector_type(8))) unsigned short u16x8;
typedef __attribute__((ext_vector_type(4))) float f32x4;

__device__ __forceinline__ unsigned short f2bf(float f) {
  union { float f; uint32_t u; } c; c.f = f;
  uint32_t r = (c.u + 0x7FFFu + ((c.u >> 16) & 1u)) >> 16;
  return (unsigned short)r;
}
__device__ __forceinline__ float bf2f(unsigned short h) {
  union { uint32_t u; float f; } c; c.u = ((uint32_t)h) << 16;
  return c.f;
}

// ---------------- mask parse: query_mask (bool/int32/f32) -> float 0/1 -------
__global__ __launch_bounds__(256) void mask_parse(const void* __restrict__ qm,
                                                  float* __restrict__ kvm) {
  unsigned w0 = *(const unsigned*)qm;
  int idx = blockIdx.x * 256 + threadIdx.x;  // 0..8191
  float v;
  if (w0 == 0x01010101u)       v = ((const unsigned char*)qm)[idx] ? 1.f : 0.f;
  else if (w0 == 0x3F800000u)  v = (((const float*)qm)[idx] != 0.f) ? 1.f : 0.f;
  else                         v = (((const int*)qm)[idx] != 0) ? 1.f : 0.f;
  kvm[idx] = v;
}

// ---------------- f32 -> bf16 elementwise ------------------------------------
__global__ __launch_bounds__(256) void cvt_f32_bf16(const float* __restrict__ in,
                                                    unsigned short* __restrict__ out,
                                                    int n) {
  int i = (blockIdx.x * 256 + threadIdx.x) * 4;
  if (i + 3 < n) {
    float4 v = *(const float4*)&in[i];
    u16x8 o8;  // use low 4
    o8[0] = f2bf(v.x); o8[1] = f2bf(v.y); o8[2] = f2bf(v.z); o8[3] = f2bf(v.w);
    out[i+0] = o8[0]; out[i+1] = o8[1]; out[i+2] = o8[2]; out[i+3] = o8[3];
  }
}

// ---------------- transpose + convert: in K x N f32 -> out N x K bf16 --------
__global__ __launch_bounds__(256) void transpose_cvt(const float* __restrict__ in,
                                                     unsigned short* __restrict__ out,
                                                     int K, int N) {
  __shared__ float tile[32][33];
  int n0 = blockIdx.x * 32, k0 = blockIdx.y * 32;
  int tx = threadIdx.x, ty = threadIdx.y;  // 32 x 8
  #pragma unroll
  for (int i = 0; i < 4; i++)
    tile[ty + i*8][tx] = in[(size_t)(k0 + ty + i*8) * N + n0 + tx];
  __syncthreads();
  #pragma unroll
  for (int i = 0; i < 4; i++)
    out[(size_t)(n0 + ty + i*8) * K + k0 + tx] = f2bf(tile[tx][ty + i*8]);
}

// ---------------- bf16 MFMA GEMM, A (Mx768) @ BT^T (768xN), 128x128 tile -----
// MODE 0: QKV epilogue (+bias, split into Q(*0.125)/K/V [B,H,T,64] bf16)
// MODE 1: proj epilogue (+bias, fp32 out)
template<int MODE>
__global__ __launch_bounds__(256) void gemm_bt(
    const unsigned short* __restrict__ A,    // M x 768 bf16 row-major
    const unsigned short* __restrict__ BT,   // N x 768 bf16 row-major (B transposed)
    const float* __restrict__ bias,          // N
    unsigned short* __restrict__ Qo, unsigned short* __restrict__ Ko,
    unsigned short* __restrict__ Vo,
    float* __restrict__ Out) {
  __shared__ unsigned short As[128 * 32];
  __shared__ unsigned short Bs[128 * 32];
  const int K = 768;
  int m0 = blockIdx.x * 128, n0 = blockIdx.y * 128;
  int tid = threadIdx.x;
  int lane = tid & 63, wv = tid >> 6;
  int wr = wv >> 1, wc = wv & 1;            // wave quadrant (2x2 of 64x64)
  int l16 = lane & 15, g = lane >> 4;       // fragment coords
  f32x4 acc[4][4];
  #pragma unroll
  for (int m = 0; m < 4; m++)
    #pragma unroll
    for (int n = 0; n < 4; n++) acc[m][n] = (f32x4){0.f, 0.f, 0.f, 0.f};

  int o = tid * 16;          // byte offset within 4KB half tile
  int r0 = o >> 6;           // row 0..63
  int kb2 = (o & 63) >> 1;   // ushort col offset 0,8,16,24

  for (int k0 = 0; k0 < K; k0 += 32) {
    __syncthreads();
    #pragma unroll
    for (int i = 0; i < 2; i++) {
      *(u16x8*)((char*)As + i*4096 + o) =
          *(const u16x8*)&A[(size_t)(m0 + i*64 + r0) * K + k0 + kb2];
      *(u16x8*)((char*)Bs + i*4096 + o) =
          *(const u16x8*)&BT[(size_t)(n0 + i*64 + r0) * K + k0 + kb2];
    }
    __syncthreads();
    s16x8 af[4], bfr[4];
    #pragma unroll
    for (int m = 0; m < 4; m++)
      af[m] = *(const s16x8*)((const char*)As + ((wr*64 + m*16 + l16) * 64 + g*16));
    #pragma unroll
    for (int n = 0; n < 4; n++)
      bfr[n] = *(const s16x8*)((const char*)Bs + ((wc*64 + n*16 + l16) * 64 + g*16));
    #pragma unroll
    for (int m = 0; m < 4; m++)
      #pragma unroll
      for (int n = 0; n < 4; n++)
        acc[m][n] = __builtin_amdgcn_mfma_f32_16x16x32_bf16(af[m], bfr[n], acc[m][n], 0, 0, 0);
  }

  #pragma unroll
  for (int m = 0; m < 4; m++) {
    int row = m0 + wr*64 + m*16 + g*4;  // C/D: row = (lane>>4)*4 + reg
    #pragma unroll
    for (int n = 0; n < 4; n++) {
      int col = n0 + wc*64 + n*16 + l16;  // C/D: col = lane&15
      float bv = bias[col];
      #pragma unroll
      for (int q = 0; q < 4; q++) {
        float v = acc[m][n][q] + bv;
        int rr = row + q;
        if (MODE == 0) {
          int which = col / 768;
          int cc = col - which * 768;
          int hh = cc >> 6, d = cc & 63;
          int bb = rr >> 10, t = rr & 1023;
          size_t dst = (((size_t)bb * Hdim + hh) * Tdim + t) * HDdim + d;
          if (which == 0)      Qo[dst] = f2bf(v * 0.125f);  // fold 1/sqrt(64)
          else if (which == 1) Ko[dst] = f2bf(v);
          else                 Vo[dst] = f2bf(v);
        } else {
          Out[(size_t)rr * 768 + col] = v;
        }
      }
    }
  }
}

// ---------------- fp32 flash attention, 64 q-rows/block, 4 thr/row ----------
__global__ __launch_bounds__(256) void attn_fp32(
    const unsigned short* __restrict__ Qb, const unsigned short* __restrict__ Kb,
    const unsigned short* __restrict__ Vb, const float* __restrict__ kvm,
    unsigned short* __restrict__ attout) {
  __shared__ float Ks[64][68];
  __shared__ float Vs[64][68];
  __shared__ float kvs[64];
  int qb = blockIdx.x, h = blockIdx.y, b = blockIdx.z;
  int tid = threadIdx.x;
  int r = tid >> 2, c = tid & 3;
  int q = qb * 64 + r;
  size_t headoff = ((size_t)b * Hdim + h) * Tdim;

  float qreg[16];
  {
    const unsigned short* qp = &Qb[(headoff + q) * 64 + c * 16];
    u16x8 v0 = *(const u16x8*)qp;
    u16x8 v1 = *(const u16x8*)(qp + 8);
    #pragma unroll
    for (int j = 0; j < 8; j++) { qreg[j] = bf2f(v0[j]); qreg[8+j] = bf2f(v1[j]); }
  }
  float mrun = -1e30f, lrun = 0.f;
  float o[16];
  #pragma unroll
  for (int j = 0; j < 16; j++) o[j] = 0.f;

  for (int kt = 0; kt <= qb; kt++) {
    int k0 = kt * 64;
    __syncthreads();
    #pragma unroll
    for (int i = 0; i < 2; i++) {
      int f = tid + i * 256;       // 0..511
      int row = f >> 3, cc8 = (f & 7) * 8;
      u16x8 kv = *(const u16x8*)&Kb[(headoff + k0 + row) * 64 + cc8];
      u16x8 vv = *(const u16x8*)&Vb[(headoff + k0 + row) * 64 + cc8];
      float4 kf0, kf1, vf0, vf1;
      kf0.x=bf2f(kv[0]); kf0.y=bf2f(kv[1]); kf0.z=bf2f(kv[2]); kf0.w=bf2f(kv[3]);
      kf1.x=bf2f(kv[4]); kf1.y=bf2f(kv[5]); kf1.z=bf2f(kv[6]); kf1.w=bf2f(kv[7]);
      vf0.x=bf2f(vv[0]); vf0.y=bf2f(vv[1]); vf0.z=bf2f(vv[2]); vf0.w=bf2f(vv[3]);
      vf1.x=bf2f(vv[4]); vf1.y=bf2f(vv[5]); vf1.z=bf2f(vv[6]); vf1.w=bf2f(vv[7]);
      *(float4*)&Ks[row][cc8]     = kf0;
      *(float4*)&Ks[row][cc8 + 4] = kf1;
      *(float4*)&Vs[row][cc8]     = vf0;
      *(float4*)&Vs[row][cc8 + 4] = vf1;
    }
    if (tid < 64) kvs[tid] = kvm[b * Tdim + k0 + tid];
    __syncthreads();
    int kend = q - k0; if (kend > 63) kend = 63;
    for (int kk = 0; kk <= kend; kk++) {
      float s = 0.f;
      const float* kr = &Ks[kk][c * 16];
      #pragma unroll
      for (int j = 0; j < 16; j++) s += qreg[j] * kr[j];
      s += __shfl_xor(s, 1);
      s += __shfl_xor(s, 2);
      float sm = (kvs[kk] > 0.f) ? s : -1e30f;
      if (sm > mrun) {                 // new max: rescale old state
        float sc = __expf(mrun - sm);
        lrun *= sc;
        #pragma unroll
        for (int j = 0; j < 16; j++) o[j] *= sc;
        mrun = sm;
      }
      float p = __expf(sm - mrun);
      lrun += p;
      const float* vr = &Vs[kk][c * 16];
      #pragma unroll
      for (int j = 0; j < 16; j++) o[j] += p * vr[j];
    }
  }
  float qmv = kvm[b * Tdim + q];
  float inv = (qmv > 0.f && lrun > 0.f) ? (1.f / lrun) : 0.f;
  u16x8 o0, o1;
  #pragma unroll
  for (int j = 0; j < 8; j++) { o0[j] = f2bf(o[j] * inv); o1[j] = f2bf(o[8+j] * inv); }
  unsigned short* op = &attout[((size_t)b * Tdim + q) * 768 + h * 64 + c * 16];
  *(u16x8*)op = o0;
  *(u16x8*)(op + 8) = o1;
}

extern "C" void kernel_launch(void* const* d_in, const int* in_sizes, int n_in,
                              void* d_out, int out_size, void* d_ws, size_t ws_size,
                              hipStream_t stream) {
  const float* x  = (const float*)d_in[0];
  const void*  qmask = d_in[2];
  const float* Wa = (const float*)d_in[3];
  const float* ba = (const float*)d_in[4];
  const float* Wp = (const float*)d_in[5];
  const float* bp = (const float*)d_in[6];
  float* out = (float*)d_out;

  char* ws = (char*)d_ws;
  unsigned short* xb  = (unsigned short*)(ws + 0);          // 8192x768 bf16
  unsigned short* WaT = (unsigned short*)(ws + 12582912);   // 2304x768 bf16
  unsigned short* WpT = (unsigned short*)(ws + 16121856);   // 768x768 bf16
  unsigned short* Qb  = (unsigned short*)(ws + 17301504);   // [B,H,T,64] bf16
  unsigned short* Kb  = (unsigned short*)(ws + 29884416);
  unsigned short* Vb  = (unsigned short*)(ws + 42467328);
  unsigned short* Ab  = (unsigned short*)(ws + 55050240);   // 8192x768 bf16
  float*          kvm = (float*)(ws + 67633152);            // 8192 f32

  mask_parse<<<32, 256, 0, stream>>>(qmask, kvm);
  cvt_f32_bf16<<<6144, 256, 0, stream>>>(x, xb, NROW * 768);
  transpose_cvt<<<dim3(72, 24), dim3(32, 8), 0, stream>>>(Wa, WaT, 768, 2304);
  transpose_cvt<<<dim3(24, 24), dim3(32, 8), 0, stream>>>(Wp, WpT, 768, 768);
  gemm_bt<0><<<dim3(64, 18), 256, 0, stream>>>(xb, WaT, ba, Qb, Kb, Vb, nullptr);
  attn_fp32<<<dim3(16, 12, 8), 256, 0, stream>>>(Qb, Kb, Vb, kvm, Ab);
  gemm_bt<1><<<dim3(64, 6), 256, 0, stream>>>(Ab, WpT, bp, nullptr, nullptr, nullptr, out);
}

// Round 2
// 192.665 us; speedup vs baseline: 3.7397x; 3.7397x over previous
//
#include <hip/hip_runtime.h>
#include <stdint.h>

#define Bdim 8
#define Tdim 1024
#define Cdim 768
#define Hdim 12
#define HDdim 64
#define NROW (Bdim*Tdim)   // 8192

typedef __attribute__((ext_vector_type(8))) short s16x8;
typedef __attribute__((ext_vector_type(8))) unsigned short u16x8;
typedef __attribute__((ext_vector_type(4))) unsigned short u16x4;
typedef __attribute__((ext_vector_type(4))) float f32x4;

__device__ __forceinline__ unsigned short f2bf(float f) {
  union { float f; uint32_t u; } c; c.f = f;
  uint32_t r = (c.u + 0x7FFFu + ((c.u >> 16) & 1u)) >> 16;
  return (unsigned short)r;
}
__device__ __forceinline__ float bf2f(unsigned short h) {
  union { uint32_t u; float f; } c; c.u = ((uint32_t)h) << 16;
  return c.f;
}

// ---------------- mask parse: query_mask (bool/int32/f32) -> float 0/1 -------
__global__ __launch_bounds__(256) void mask_parse(const void* __restrict__ qm,
                                                  float* __restrict__ kvm) {
  unsigned w0 = *(const unsigned*)qm;
  int idx = blockIdx.x * 256 + threadIdx.x;  // 0..8191
  float v;
  if (w0 == 0x01010101u)       v = ((const unsigned char*)qm)[idx] ? 1.f : 0.f;
  else if (w0 == 0x3F800000u)  v = (((const float*)qm)[idx] != 0.f) ? 1.f : 0.f;
  else                         v = (((const int*)qm)[idx] != 0) ? 1.f : 0.f;
  kvm[idx] = v;
}

// ---------------- f32 -> bf16 elementwise ------------------------------------
__global__ __launch_bounds__(256) void cvt_f32_bf16(const float* __restrict__ in,
                                                    unsigned short* __restrict__ out,
                                                    int n) {
  int i = (blockIdx.x * 256 + threadIdx.x) * 4;
  if (i + 3 < n) {
    float4 v = *(const float4*)&in[i];
    out[i+0] = f2bf(v.x); out[i+1] = f2bf(v.y);
    out[i+2] = f2bf(v.z); out[i+3] = f2bf(v.w);
  }
}

// ---------------- transpose + convert: in K x N f32 -> out N x K bf16 --------
__global__ __launch_bounds__(256) void transpose_cvt(const float* __restrict__ in,
                                                     unsigned short* __restrict__ out,
                                                     int K, int N) {
  __shared__ float tile[32][33];
  int n0 = blockIdx.x * 32, k0 = blockIdx.y * 32;
  int tx = threadIdx.x, ty = threadIdx.y;  // 32 x 8
  #pragma unroll
  for (int i = 0; i < 4; i++)
    tile[ty + i*8][tx] = in[(size_t)(k0 + ty + i*8) * N + n0 + tx];
  __syncthreads();
  #pragma unroll
  for (int i = 0; i < 4; i++)
    out[(size_t)(n0 + ty + i*8) * K + k0 + tx] = f2bf(tile[tx][ty + i*8]);
}

// ---------------- bf16 MFMA GEMM, A (Mx768) @ BT^T (768xN), 128x128 tile -----
// MODE 0: QKV epilogue (+bias, split: Q(*0.125) [B,H,T,64], K [B,H,T,64],
//                       V TRANSPOSED as [B,H,64,T])
// MODE 1: proj epilogue (+bias, fp32 out)
template<int MODE>
__global__ __launch_bounds__(256) void gemm_bt(
    const unsigned short* __restrict__ A,    // M x 768 bf16 row-major
    const unsigned short* __restrict__ BT,   // N x 768 bf16 row-major
    const float* __restrict__ bias,          // N
    unsigned short* __restrict__ Qo, unsigned short* __restrict__ Ko,
    unsigned short* __restrict__ Vo,
    float* __restrict__ Out) {
  __shared__ unsigned short As[128 * 32];
  __shared__ unsigned short Bs[128 * 32];
  const int K = 768;
  int m0 = blockIdx.x * 128, n0 = blockIdx.y * 128;
  int tid = threadIdx.x;
  int lane = tid & 63, wv = tid >> 6;
  int wr = wv >> 1, wc = wv & 1;
  int l16 = lane & 15, g = lane >> 4;
  f32x4 acc[4][4];
  #pragma unroll
  for (int m = 0; m < 4; m++)
    #pragma unroll
    for (int n = 0; n < 4; n++) acc[m][n] = (f32x4){0.f, 0.f, 0.f, 0.f};

  int o = tid * 16;
  int r0 = o >> 6;
  int kb2 = (o & 63) >> 1;

  for (int k0 = 0; k0 < K; k0 += 32) {
    __syncthreads();
    #pragma unroll
    for (int i = 0; i < 2; i++) {
      *(u16x8*)((char*)As + i*4096 + o) =
          *(const u16x8*)&A[(size_t)(m0 + i*64 + r0) * K + k0 + kb2];
      *(u16x8*)((char*)Bs + i*4096 + o) =
          *(const u16x8*)&BT[(size_t)(n0 + i*64 + r0) * K + k0 + kb2];
    }
    __syncthreads();
    s16x8 af[4], bfr[4];
    #pragma unroll
    for (int m = 0; m < 4; m++)
      af[m] = *(const s16x8*)((const char*)As + ((wr*64 + m*16 + l16) * 64 + g*16));
    #pragma unroll
    for (int n = 0; n < 4; n++)
      bfr[n] = *(const s16x8*)((const char*)Bs + ((wc*64 + n*16 + l16) * 64 + g*16));
    #pragma unroll
    for (int m = 0; m < 4; m++)
      #pragma unroll
      for (int n = 0; n < 4; n++)
        acc[m][n] = __builtin_amdgcn_mfma_f32_16x16x32_bf16(af[m], bfr[n], acc[m][n], 0, 0, 0);
  }

  #pragma unroll
  for (int m = 0; m < 4; m++) {
    int row = m0 + wr*64 + m*16 + g*4;
    #pragma unroll
    for (int n = 0; n < 4; n++) {
      int col = n0 + wc*64 + n*16 + l16;
      float bv = bias[col];
      #pragma unroll
      for (int q = 0; q < 4; q++) {
        float v = acc[m][n][q] + bv;
        int rr = row + q;
        if (MODE == 0) {
          int which = col / 768;
          int cc = col - which * 768;
          int hh = cc >> 6, d = cc & 63;
          int bb = rr >> 10, t = rr & 1023;
          if (which == 0)
            Qo[(((size_t)bb * Hdim + hh) * Tdim + t) * HDdim + d] = f2bf(v * 0.125f);
          else if (which == 1)
            Ko[(((size_t)bb * Hdim + hh) * Tdim + t) * HDdim + d] = f2bf(v);
          else  // V transposed: [B,H,64,T]
            Vo[(((size_t)bb * Hdim + hh) * HDdim + d) * Tdim + t] = f2bf(v);
        } else {
          Out[(size_t)rr * 768 + col] = v;
        }
      }
    }
  }
}

// ---------------- MFMA flash attention ---------------------------------------
// 4 waves x 32 q-rows = 128 q/block. KV tile 64. Swapped QK^T (S^T = K.Q^T)
// so softmax packs; PV standard with V^T staged from d-major global V.
__global__ __launch_bounds__(256) void attn_mfma(
    const unsigned short* __restrict__ Qb,  // [B,H,T,64]  (pre-scaled by 0.125)
    const unsigned short* __restrict__ Kb,  // [B,H,T,64]
    const unsigned short* __restrict__ Vt,  // [B,H,64,T]
    const float* __restrict__ kvm,          // [B*T] 0/1
    unsigned short* __restrict__ attout) {  // [B*T, 768] bf16
  __shared__ unsigned short Ks[64 * 64];    // swizzled [k][d]
  __shared__ unsigned short Vs[64 * 64];    // swizzled [d][k]
  __shared__ unsigned short Ps[4][32 * 64]; // swizzled per-wave [q][k]
  __shared__ float kvs[64];

  const int qb = blockIdx.x, h = blockIdx.y, b = blockIdx.z;
  const int q0 = qb * 128;
  const int tid = threadIdx.x;
  const int lane = tid & 63, w = tid >> 6;
  const int l16 = lane & 15, g = lane >> 4;
  const size_t head = ((size_t)b * Hdim + h) * Tdim;
  const unsigned short* qh = Qb + head * 64;
  const unsigned short* kh = Kb + head * 64;
  const unsigned short* vh = Vt + head * 64;
  const int q0w = q0 + w * 32;
  const int swz = (l16 & 7) << 4;

  // Q fragments in registers: q = q0w + jt*16 + l16, d = kc*32 + g*8 + j
  s16x8 qf[2][2];
  #pragma unroll
  for (int jt = 0; jt < 2; jt++)
    #pragma unroll
    for (int kc = 0; kc < 2; kc++)
      qf[jt][kc] = *(const s16x8*)&qh[(size_t)(q0w + jt*16 + l16) * 64 + kc*32 + g*8];

  float m_r[2] = {-1e30f, -1e30f};
  float l_r[2] = {0.f, 0.f};
  f32x4 oacc[2][4];
  #pragma unroll
  for (int mt = 0; mt < 2; mt++)
    #pragma unroll
    for (int nt = 0; nt < 4; nt++) oacc[mt][nt] = (f32x4){0.f, 0.f, 0.f, 0.f};

  const int ntiles = qb * 2 + 2;
  const int wqmax = q0w + 31;

  for (int kt = 0; kt < ntiles; kt++) {
    const int kv0 = kt * 64;
    __syncthreads();
    // stage K [k][d] and V^T [d][k], XOR-swizzled; 2 passes x 256 thr x 16B
    #pragma unroll
    for (int it = 0; it < 2; it++) {
      int off = tid * 8 + it * 2048;
      int r = off >> 6, c = off & 63;
      int sw = (r & 7) << 4;
      *(u16x8*)((char*)Ks + ((r*128 + c*2) ^ sw)) =
          *(const u16x8*)&kh[(size_t)(kv0 + r) * 64 + c];
      *(u16x8*)((char*)Vs + ((r*128 + c*2) ^ sw)) =
          *(const u16x8*)&vh[(size_t)r * Tdim + kv0 + c];
    }
    if (tid < 64) kvs[tid] = kvm[b * Tdim + kv0 + tid];
    __syncthreads();
    if (kv0 > wqmax) continue;  // fully masked for this wave; barriers stay matched

    // S^T = K . Q^T : St[it][jt], lane: k = kv0+it*16+g*4+reg, q = q0w+jt*16+l16
    f32x4 st[4][2];
    #pragma unroll
    for (int it = 0; it < 4; it++)
      #pragma unroll
      for (int jt = 0; jt < 2; jt++) st[it][jt] = (f32x4){0.f, 0.f, 0.f, 0.f};
    #pragma unroll
    for (int kc = 0; kc < 2; kc++) {
      s16x8 kf[4];
      #pragma unroll
      for (int it = 0; it < 4; it++) {
        int row = it*16 + l16;
        kf[it] = *(const s16x8*)((const char*)Ks + ((row*128 + kc*64 + g*16) ^ swz));
      }
      #pragma unroll
      for (int it = 0; it < 4; it++)
        #pragma unroll
        for (int jt = 0; jt < 2; jt++)
          st[it][jt] = __builtin_amdgcn_mfma_f32_16x16x32_bf16(kf[it], qf[jt][kc], st[it][jt], 0, 0, 0);
    }

    // key-valid per (it,reg)
    float kvq[4][4];
    #pragma unroll
    for (int it = 0; it < 4; it++) {
      float4 kq = *(const float4*)&kvs[it*16 + g*4];
      kvq[it][0] = kq.x; kvq[it][1] = kq.y; kvq[it][2] = kq.z; kvq[it][3] = kq.w;
    }

    float scjt[2];
    #pragma unroll
    for (int jt = 0; jt < 2; jt++) {
      const int qg = q0w + jt*16 + l16;
      float pmax = -1e30f;
      #pragma unroll
      for (int it = 0; it < 4; it++)
        #pragma unroll
        for (int reg = 0; reg < 4; reg++) {
          int kg = kv0 + it*16 + g*4 + reg;
          float s = (kg <= qg && kvq[it][reg] > 0.f) ? st[it][jt][reg] : -1e30f;
          st[it][jt][reg] = s;
          pmax = fmaxf(pmax, s);
        }
      pmax = fmaxf(pmax, __shfl_xor(pmax, 16));
      pmax = fmaxf(pmax, __shfl_xor(pmax, 32));
      float mnew = fmaxf(m_r[jt], pmax);
      float sc = __expf(m_r[jt] - mnew);   // 1.0 when unchanged (incl. -1e30-(-1e30)=0)
      m_r[jt] = mnew;
      scjt[jt] = sc;
      float psum = 0.f;
      u16x4 pw[4];
      #pragma unroll
      for (int it = 0; it < 4; it++)
        #pragma unroll
        for (int reg = 0; reg < 4; reg++) {
          float p = __expf(st[it][jt][reg] - mnew);  // masked -> exp(-1e30) = 0
          psum += p;
          pw[it][reg] = f2bf(p);
        }
      psum += __shfl_xor(psum, 16);
      psum += __shfl_xor(psum, 32);
      l_r[jt] = l_r[jt] * sc + psum;
      const int prow = jt*16 + l16;
      #pragma unroll
      for (int it = 0; it < 4; it++)
        *(u16x4*)((char*)Ps[w] + ((prow*128 + it*32 + g*8) ^ swz)) = pw[it];
    }

    // rescale O: O rows q = mt*16 + g*4 + reg; scale lives on lane l16 = q&15
    #pragma unroll
    for (int mt = 0; mt < 2; mt++)
      #pragma unroll
      for (int reg = 0; reg < 4; reg++) {
        float s = __shfl(scjt[mt], (lane & 48) | (g*4 + reg));
        #pragma unroll
        for (int nt = 0; nt < 4; nt++) oacc[mt][nt][reg] *= s;
      }

    // PV: O += P . V  (A = P rows q, B^T = V^T rows d)
    #pragma unroll
    for (int kc = 0; kc < 2; kc++) {
      s16x8 pa[2], vf[4];
      #pragma unroll
      for (int mt = 0; mt < 2; mt++) {
        int row = mt*16 + l16;
        pa[mt] = *(const s16x8*)((const char*)Ps[w] + ((row*128 + kc*64 + g*16) ^ swz));
      }
      #pragma unroll
      for (int nt = 0; nt < 4; nt++) {
        int row = nt*16 + l16;
        vf[nt] = *(const s16x8*)((const char*)Vs + ((row*128 + kc*64 + g*16) ^ swz));
      }
      #pragma unroll
      for (int mt = 0; mt < 2; mt++)
        #pragma unroll
        for (int nt = 0; nt < 4; nt++)
          oacc[mt][nt] = __builtin_amdgcn_mfma_f32_16x16x32_bf16(pa[mt], vf[nt], oacc[mt][nt], 0, 0, 0);
    }
  }

  // epilogue: normalize by l, apply query mask, write bf16
  float iv[2];
  #pragma unroll
  for (int jt = 0; jt < 2; jt++) {
    int qg = q0w + jt*16 + l16;
    float qmv = kvm[b * Tdim + qg];
    iv[jt] = (qmv > 0.f && l_r[jt] > 0.f) ? (1.f / l_r[jt]) : 0.f;
  }
  #pragma unroll
  for (int mt = 0; mt < 2; mt++)
    #pragma unroll
    for (int reg = 0; reg < 4; reg++) {
      float ivv = __shfl(iv[mt], (lane & 48) | (g*4 + reg));
      int qg = q0w + mt*16 + g*4 + reg;
      unsigned short* op = &attout[(size_t)(b * Tdim + qg) * 768 + h * 64];
      #pragma unroll
      for (int nt = 0; nt < 4; nt++)
        op[nt*16 + l16] = f2bf(oacc[mt][nt][reg] * ivv);
    }
}

extern "C" void kernel_launch(void* const* d_in, const int* in_sizes, int n_in,
                              void* d_out, int out_size, void* d_ws, size_t ws_size,
                              hipStream_t stream) {
  const float* x  = (const float*)d_in[0];
  const void*  qmask = d_in[2];
  const float* Wa = (const float*)d_in[3];
  const float* ba = (const float*)d_in[4];
  const float* Wp = (const float*)d_in[5];
  const float* bp = (const float*)d_in[6];
  float* out = (float*)d_out;

  char* ws = (char*)d_ws;
  unsigned short* xb  = (unsigned short*)(ws + 0);          // 8192x768 bf16
  unsigned short* WaT = (unsigned short*)(ws + 12582912);   // 2304x768 bf16
  unsigned short* WpT = (unsigned short*)(ws + 16121856);   // 768x768 bf16
  unsigned short* Qb  = (unsigned short*)(ws + 17301504);   // [B,H,T,64] bf16
  unsigned short* Kb  = (unsigned short*)(ws + 29884416);   // [B,H,T,64] bf16
  unsigned short* Vb  = (unsigned short*)(ws + 42467328);   // [B,H,64,T] bf16
  unsigned short* Ab  = (unsigned short*)(ws + 55050240);   // 8192x768 bf16
  float*          kvm = (float*)(ws + 67633152);            // 8192 f32

  mask_parse<<<32, 256, 0, stream>>>(qmask, kvm);
  cvt_f32_bf16<<<6144, 256, 0, stream>>>(x, xb, NROW * 768);
  transpose_cvt<<<dim3(72, 24), dim3(32, 8), 0, stream>>>(Wa, WaT, 768, 2304);
  transpose_cvt<<<dim3(24, 24), dim3(32, 8), 0, stream>>>(Wp, WpT, 768, 768);
  gemm_bt<0><<<dim3(64, 18), 256, 0, stream>>>(xb, WaT, ba, Qb, Kb, Vb, nullptr);
  attn_mfma<<<dim3(8, 12, 8), 256, 0, stream>>>(Qb, Kb, Vb, kvm, Ab);
  gemm_bt<1><<<dim3(64, 6), 256, 0, stream>>>(Ab, WpT, bp, nullptr, nullptr, nullptr, out);
}